// Round 1
// baseline (52.473 us; speedup 1.0000x reference)
//
#include <hip/hip_runtime.h>
#include <hip/hip_bf16.h>

// MiniBatchDiscrimination: out = concat([x, sum_b2 exp(-L1(act_b, act_b2))], axis=1)
// B=512, F=512, K=50, D=16.  act = x @ W : (512, 800) fp32.

#define B_ROWS 512
#define F_IN   512
#define NK     50
#define DK     16
#define N_COLS (NK * DK)      // 800
#define OUT_COLS (F_IN + NK)  // 562

#if __has_builtin(__builtin_amdgcn_exp2f)
#define EXP2F __builtin_amdgcn_exp2f
#else
#define EXP2F exp2f
#endif

// ---------------- GEMM: act[512][800] = x[512][512] @ W[512][800] ----------------
// BM=64, BN=32, BK=32, 256 threads, thread tile 4(m) x 2(n). Grid (25, 8) = 200 blocks.
__global__ __launch_bounds__(256) void gemm_kernel(const float* __restrict__ x,
                                                   const float* __restrict__ W,
                                                   float* __restrict__ act) {
    __shared__ float As[32][68];  // As[kk][m], 68-pad: rows 272B (16B aligned), conflict-free b128 reads
    __shared__ float Bs[32][36];  // Bs[kk][n], 36-pad: rows 144B (16B aligned)

    const int tid = threadIdx.x;
    const int nBase = blockIdx.x * 32;   // 25 tiles
    const int mBase = blockIdx.y * 64;   // 8 tiles
    const int tm = tid >> 4;             // 0..15 -> rows m0 = tm*4
    const int tn = tid & 15;             // 0..15 -> cols n0 = tn*2

    float acc[4][2] = {};

    for (int k0 = 0; k0 < F_IN; k0 += 32) {
        // stage A tile: 64 rows x 32 k -> As[kk][m]; 512 float4, 2 per thread
        #pragma unroll
        for (int i = 0; i < 2; ++i) {
            int idx = tid + i * 256;           // 0..511
            int r = idx >> 3;                  // 0..63
            int kq = idx & 7;                  // 0..7
            float4 v = *(const float4*)(x + (mBase + r) * F_IN + k0 + 4 * kq);
            As[4 * kq + 0][r] = v.x;
            As[4 * kq + 1][r] = v.y;
            As[4 * kq + 2][r] = v.z;
            As[4 * kq + 3][r] = v.w;
        }
        // stage B tile: 32 k x 32 n; 256 float4, 1 per thread
        {
            int r = tid >> 3;                  // kk 0..31
            int cq = tid & 7;                  // 0..7
            *(float4*)&Bs[r][4 * cq] = *(const float4*)(W + (k0 + r) * N_COLS + nBase + 4 * cq);
        }
        __syncthreads();

        #pragma unroll
        for (int kk = 0; kk < 32; ++kk) {
            float4 a = *(const float4*)&As[kk][tm * 4];
            float2 b = *(const float2*)&Bs[kk][tn * 2];
            acc[0][0] += a.x * b.x; acc[0][1] += a.x * b.y;
            acc[1][0] += a.y * b.x; acc[1][1] += a.y * b.y;
            acc[2][0] += a.z * b.x; acc[2][1] += a.z * b.y;
            acc[3][0] += a.w * b.x; acc[3][1] += a.w * b.y;
        }
        __syncthreads();
    }

    #pragma unroll
    for (int i = 0; i < 4; ++i) {
        *(float2*)(act + (mBase + tm * 4 + i) * N_COLS + nBase + tn * 2) =
            make_float2(acc[i][0], acc[i][1]);
    }
}

// ---------------- Pairwise L1 + exp-sum ----------------
// Grid (50, 16): one block per (kernel k, 32-row chunk). 256 threads.
// Block stages act[:, k, :] (512 x 16 f32 = 32 KB) in LDS.
// Thread = (row within chunk, q in 0..7); q owns a 64-wide b2 range.
__global__ __launch_bounds__(256) void pairwise_kernel(const float* __restrict__ act,
                                                       float* __restrict__ out) {
    const int k = blockIdx.x;          // 0..49
    const int chunk = blockIdx.y;      // 0..15
    __shared__ float4 Av[B_ROWS * 4];  // Av[b*4 + d4], 32 KB

    const int tid = threadIdx.x;
    const float* base = act + k * DK;
    #pragma unroll
    for (int i = 0; i < 8; ++i) {
        int idx = tid + i * 256;       // 0..2047
        int b = idx >> 2, d4 = idx & 3;
        Av[idx] = *(const float4*)(base + b * N_COLS + d4 * 4);
    }
    __syncthreads();

    const int row = chunk * 32 + (tid >> 3);
    const int q = tid & 7;
    // per-q rotation of the float4 index so the 8 q-groups hit distinct banks
    const int c0 = q & 3, c1 = (q + 1) & 3, c2 = (q + 2) & 3, c3 = (q + 3) & 3;

    const float4 m0 = Av[row * 4 + c0];
    const float4 m1 = Av[row * 4 + c1];
    const float4 m2 = Av[row * 4 + c2];
    const float4 m3 = Av[row * 4 + c3];

    float acc = 0.f;
    int b2 = q * 64;
    #pragma unroll 4
    for (int i = 0; i < 64; ++i, ++b2) {
        float4 v0 = Av[b2 * 4 + c0];
        float4 v1 = Av[b2 * 4 + c1];
        float4 v2 = Av[b2 * 4 + c2];
        float4 v3 = Av[b2 * 4 + c3];
        float s0 = fabsf(m0.x - v0.x) + fabsf(m0.y - v0.y) + fabsf(m0.z - v0.z) + fabsf(m0.w - v0.w);
        float s1 = fabsf(m1.x - v1.x) + fabsf(m1.y - v1.y) + fabsf(m1.z - v1.z) + fabsf(m1.w - v1.w);
        float s2 = fabsf(m2.x - v2.x) + fabsf(m2.y - v2.y) + fabsf(m2.z - v2.z) + fabsf(m2.w - v2.w);
        float s3 = fabsf(m3.x - v3.x) + fabsf(m3.y - v3.y) + fabsf(m3.z - v3.z) + fabsf(m3.w - v3.w);
        float l1 = (s0 + s1) + (s2 + s3);
        acc += EXP2F(l1 * -1.4426950408889634f);
    }
    acc += __shfl_xor(acc, 1);
    acc += __shfl_xor(acc, 2);
    acc += __shfl_xor(acc, 4);
    if (q == 0) out[row * OUT_COLS + F_IN + k] = acc;
}

// ---------------- passthrough copy of x into out[:, 0:512] ----------------
__global__ __launch_bounds__(256) void copy_x_kernel(const float* __restrict__ x,
                                                     float* __restrict__ out) {
    int idx = blockIdx.x * 256 + threadIdx.x;   // 0..131071 (512 rows x 256 float2)
    int b = idx >> 8;
    int c2 = idx & 255;
    float2 v = ((const float2*)x)[idx];
    *(float2*)(out + b * OUT_COLS + 2 * c2) = v;   // 562 even -> 8B aligned
}

extern "C" void kernel_launch(void* const* d_in, const int* in_sizes, int n_in,
                              void* d_out, int out_size, void* d_ws, size_t ws_size,
                              hipStream_t stream) {
    const float* x = (const float*)d_in[0];   // (512, 512)
    const float* W = (const float*)d_in[1];   // (512, 800)
    float* out = (float*)d_out;               // (512, 562)
    float* act = (float*)d_ws;                // (512, 800) scratch

    gemm_kernel<<<dim3(25, 8), dim3(256), 0, stream>>>(x, W, act);
    pairwise_kernel<<<dim3(50, 16), dim3(256), 0, stream>>>(act, out);
    copy_x_kernel<<<dim3(512), dim3(256), 0, stream>>>(x, out);
}

// Round 2
// 43.780 us; speedup vs baseline: 1.1986x; 1.1986x over previous
//
#include <hip/hip_runtime.h>
#include <hip/hip_bf16.h>

// MiniBatchDiscrimination: out = concat([x, sum_b2 exp(-L1(act_b, act_b2))], axis=1)
// B=512, F=512, K=50, D=16.  act = x @ W : (512, 800).
// Round 2: bf16 MFMA GEMM (zero-LDS, direct-global fragments) + fused cast/copy/transpose prep.

#define B_ROWS 512
#define F_IN   512
#define NK     50
#define DK     16
#define N_COLS (NK * DK)      // 800
#define OUT_COLS (F_IN + NK)  // 562

#if __has_builtin(__builtin_amdgcn_exp2f)
#define EXP2F __builtin_amdgcn_exp2f
#else
#define EXP2F exp2f
#endif

typedef __attribute__((ext_vector_type(8))) short bf16x8;
typedef __attribute__((ext_vector_type(4))) float f32x4;

__device__ __forceinline__ ushort f2bf(float f) {
    union { float f; unsigned u; } v; v.f = f;
    unsigned r = v.u + 0x7FFFu + ((v.u >> 16) & 1u);   // RNE
    return (ushort)(r >> 16);
}

// ---------------- prep: cast x -> bf16 + passthrough copy, W -> WT bf16 ----------------
// blocks 0..127: x (512x512). blocks 128..527: W transpose tiles (32x32), 16x25 tiles.
__global__ __launch_bounds__(256) void prep_kernel(const float* __restrict__ x,
                                                   const float* __restrict__ W,
                                                   ushort* __restrict__ xb,   // 512x512 bf16
                                                   ushort* __restrict__ wt,   // 800x512 bf16 (W^T)
                                                   float* __restrict__ out) {
    const int tid = threadIdx.x;
    if (blockIdx.x < 128) {
        // x part: 65536 float4; 2 per thread
        #pragma unroll
        for (int i = 0; i < 2; ++i) {
            int idx = blockIdx.x * 256 + tid + i * 32768;
            int row = idx >> 7, c4 = idx & 127;
            float4 v = ((const float4*)x)[idx];
            // passthrough fp32 copy into out[:, 0:512] (8B-aligned only: two float2)
            float* o = out + row * OUT_COLS + c4 * 4;
            *(float2*)o = make_float2(v.x, v.y);
            *(float2*)(o + 2) = make_float2(v.z, v.w);
            // bf16 cast
            ushort4 b; b.x = f2bf(v.x); b.y = f2bf(v.y); b.z = f2bf(v.z); b.w = f2bf(v.w);
            ((ushort4*)xb)[idx] = b;
        }
    } else {
        // W transpose tile: W(512x800) fp32 -> WT(800x512) bf16
        __shared__ float Lf[32][33];
        int t = blockIdx.x - 128;          // 0..399
        int r0 = (t / 25) * 32, c0 = (t % 25) * 32;
        int ri = tid >> 3, c4 = tid & 7;
        float4 v = *(const float4*)(W + (r0 + ri) * N_COLS + c0 + 4 * c4);
        Lf[ri][4 * c4 + 0] = v.x; Lf[ri][4 * c4 + 1] = v.y;
        Lf[ri][4 * c4 + 2] = v.z; Lf[ri][4 * c4 + 3] = v.w;
        __syncthreads();
        int ci = tid >> 3, rq = tid & 7;
        ushort4 b;
        b.x = f2bf(Lf[4 * rq + 0][ci]);
        b.y = f2bf(Lf[4 * rq + 1][ci]);
        b.z = f2bf(Lf[4 * rq + 2][ci]);
        b.w = f2bf(Lf[4 * rq + 3][ci]);
        *(ushort4*)(wt + (c0 + ci) * F_IN + r0 + 4 * rq) = b;
    }
}

// ---------------- GEMM: act[512][800] = xb @ WT^T via 16x16x32 bf16 MFMA ----------------
// 1 wave per block; block (mb, nb) computes rows mb*16..+15, cols nb*32..+31 (2 frags).
// A frag: lane l holds x[mBase + (l&15)][k0 + 8*(l>>4) + j]  (16B contiguous load)
// B frag: lane l holds W[k0 + 8*(l>>4) + j][nBase + (l&15)] = WT[nBase+(l&15)][...]  (16B load)
// C/D:    col = l&15, row = (l>>4)*4 + reg   [m89 verified]
__global__ __launch_bounds__(64) void gemm_mfma_kernel(const ushort* __restrict__ xb,
                                                       const ushort* __restrict__ wt,
                                                       float* __restrict__ act) {
    const int l = threadIdx.x;
    const int mBase = blockIdx.x * 16;
    const int nBase = blockIdx.y * 32;
    const int rc = l & 15, kg = l >> 2 >> 2;  // kg = l>>4, 0..3

    const ushort* pa  = xb + (mBase + rc) * F_IN + kg * 8;
    const ushort* pb0 = wt + (nBase + rc) * F_IN + kg * 8;
    const ushort* pb1 = pb0 + 16 * F_IN;

    f32x4 acc0 = {0.f, 0.f, 0.f, 0.f};
    f32x4 acc1 = {0.f, 0.f, 0.f, 0.f};

    #pragma unroll
    for (int ks = 0; ks < 16; ++ks) {
        bf16x8 a  = *(const bf16x8*)(pa  + ks * 32);
        bf16x8 b0 = *(const bf16x8*)(pb0 + ks * 32);
        bf16x8 b1 = *(const bf16x8*)(pb1 + ks * 32);
        acc0 = __builtin_amdgcn_mfma_f32_16x16x32_bf16(a, b0, acc0, 0, 0, 0);
        acc1 = __builtin_amdgcn_mfma_f32_16x16x32_bf16(a, b1, acc1, 0, 0, 0);
    }

    #pragma unroll
    for (int r = 0; r < 4; ++r) {
        act[(mBase + kg * 4 + r) * N_COLS + nBase + rc]      = acc0[r];
        act[(mBase + kg * 4 + r) * N_COLS + nBase + 16 + rc] = acc1[r];
    }
}

// ---------------- Pairwise L1 + exp-sum (unchanged from round 1) ----------------
__global__ __launch_bounds__(256) void pairwise_kernel(const float* __restrict__ act,
                                                       float* __restrict__ out) {
    const int k = blockIdx.x;          // 0..49
    const int chunk = blockIdx.y;      // 0..15
    __shared__ float4 Av[B_ROWS * 4];  // 32 KB

    const int tid = threadIdx.x;
    const float* base = act + k * DK;
    #pragma unroll
    for (int i = 0; i < 8; ++i) {
        int idx = tid + i * 256;
        int b = idx >> 2, d4 = idx & 3;
        Av[idx] = *(const float4*)(base + b * N_COLS + d4 * 4);
    }
    __syncthreads();

    const int row = chunk * 32 + (tid >> 3);
    const int q = tid & 7;
    const int c0 = q & 3, c1 = (q + 1) & 3, c2 = (q + 2) & 3, c3 = (q + 3) & 3;

    const float4 m0 = Av[row * 4 + c0];
    const float4 m1 = Av[row * 4 + c1];
    const float4 m2 = Av[row * 4 + c2];
    const float4 m3 = Av[row * 4 + c3];

    float acc = 0.f;
    int b2 = q * 64;
    #pragma unroll 4
    for (int i = 0; i < 64; ++i, ++b2) {
        float4 v0 = Av[b2 * 4 + c0];
        float4 v1 = Av[b2 * 4 + c1];
        float4 v2 = Av[b2 * 4 + c2];
        float4 v3 = Av[b2 * 4 + c3];
        float s0 = fabsf(m0.x - v0.x) + fabsf(m0.y - v0.y) + fabsf(m0.z - v0.z) + fabsf(m0.w - v0.w);
        float s1 = fabsf(m1.x - v1.x) + fabsf(m1.y - v1.y) + fabsf(m1.z - v1.z) + fabsf(m1.w - v1.w);
        float s2 = fabsf(m2.x - v2.x) + fabsf(m2.y - v2.y) + fabsf(m2.z - v2.z) + fabsf(m2.w - v2.w);
        float s3 = fabsf(m3.x - v3.x) + fabsf(m3.y - v3.y) + fabsf(m3.z - v3.z) + fabsf(m3.w - v3.w);
        float l1 = (s0 + s1) + (s2 + s3);
        acc += EXP2F(l1 * -1.4426950408889634f);
    }
    acc += __shfl_xor(acc, 1);
    acc += __shfl_xor(acc, 2);
    acc += __shfl_xor(acc, 4);
    if (q == 0) out[row * OUT_COLS + F_IN + k] = acc;
}

extern "C" void kernel_launch(void* const* d_in, const int* in_sizes, int n_in,
                              void* d_out, int out_size, void* d_ws, size_t ws_size,
                              hipStream_t stream) {
    const float* x = (const float*)d_in[0];   // (512, 512) fp32
    const float* W = (const float*)d_in[1];   // (512, 800) fp32
    float* out = (float*)d_out;               // (512, 562) fp32

    char* ws = (char*)d_ws;
    ushort* xb = (ushort*)ws;                          // 512x512 bf16 = 512 KB
    ushort* wt = (ushort*)(ws + (512 * 1024));         // 800x512 bf16 = 800 KB
    float* act = (float*)(ws + (512 + 800) * 1024);    // 512x800 f32 = 1.6 MB

    prep_kernel<<<dim3(528), dim3(256), 0, stream>>>(x, W, xb, wt, out);
    gemm_mfma_kernel<<<dim3(32, 25), dim3(64), 0, stream>>>(xb, wt, act);
    pairwise_kernel<<<dim3(50, 16), dim3(256), 0, stream>>>(act, out);
}

// Round 3
// 39.877 us; speedup vs baseline: 1.3159x; 1.0979x over previous
//
#include <hip/hip_runtime.h>
#include <hip/hip_bf16.h>

// MiniBatchDiscrimination: out = concat([x, sum_b2 exp(-L1(act_b, act_b2))], axis=1)
// B=512, F=512, K=50, D=16.  act = x @ W : (512, 800).
// Round 3: pairwise register-blocked 4 rows/thread (4x fewer LDS reads) + XOR bank swizzle.

#define B_ROWS 512
#define F_IN   512
#define NK     50
#define DK     16
#define N_COLS (NK * DK)      // 800
#define OUT_COLS (F_IN + NK)  // 562

#if __has_builtin(__builtin_amdgcn_exp2f)
#define EXP2F __builtin_amdgcn_exp2f
#else
#define EXP2F exp2f
#endif

typedef __attribute__((ext_vector_type(8))) short bf16x8;
typedef __attribute__((ext_vector_type(4))) float f32x4;

__device__ __forceinline__ ushort f2bf(float f) {
    union { float f; unsigned u; } v; v.f = f;
    unsigned r = v.u + 0x7FFFu + ((v.u >> 16) & 1u);   // RNE
    return (ushort)(r >> 16);
}

// ---------------- prep: cast x -> bf16 + passthrough copy, W -> WT bf16 ----------------
__global__ __launch_bounds__(256) void prep_kernel(const float* __restrict__ x,
                                                   const float* __restrict__ W,
                                                   ushort* __restrict__ xb,   // 512x512 bf16
                                                   ushort* __restrict__ wt,   // 800x512 bf16 (W^T)
                                                   float* __restrict__ out) {
    const int tid = threadIdx.x;
    if (blockIdx.x < 128) {
        #pragma unroll
        for (int i = 0; i < 2; ++i) {
            int idx = blockIdx.x * 256 + tid + i * 32768;
            int row = idx >> 7, c4 = idx & 127;
            float4 v = ((const float4*)x)[idx];
            float* o = out + row * OUT_COLS + c4 * 4;
            *(float2*)o = make_float2(v.x, v.y);
            *(float2*)(o + 2) = make_float2(v.z, v.w);
            ushort4 b; b.x = f2bf(v.x); b.y = f2bf(v.y); b.z = f2bf(v.z); b.w = f2bf(v.w);
            ((ushort4*)xb)[idx] = b;
        }
    } else {
        __shared__ float Lf[32][33];
        int t = blockIdx.x - 128;          // 0..399
        int r0 = (t / 25) * 32, c0 = (t % 25) * 32;
        int ri = tid >> 3, c4 = tid & 7;
        float4 v = *(const float4*)(W + (r0 + ri) * N_COLS + c0 + 4 * c4);
        Lf[ri][4 * c4 + 0] = v.x; Lf[ri][4 * c4 + 1] = v.y;
        Lf[ri][4 * c4 + 2] = v.z; Lf[ri][4 * c4 + 3] = v.w;
        __syncthreads();
        int ci = tid >> 3, rq = tid & 7;
        ushort4 b;
        b.x = f2bf(Lf[4 * rq + 0][ci]);
        b.y = f2bf(Lf[4 * rq + 1][ci]);
        b.z = f2bf(Lf[4 * rq + 2][ci]);
        b.w = f2bf(Lf[4 * rq + 3][ci]);
        *(ushort4*)(wt + (c0 + ci) * F_IN + r0 + 4 * rq) = b;
    }
}

// ---------------- GEMM: act[512][800] = xb @ WT^T via 16x16x32 bf16 MFMA ----------------
__global__ __launch_bounds__(64) void gemm_mfma_kernel(const ushort* __restrict__ xb,
                                                       const ushort* __restrict__ wt,
                                                       float* __restrict__ act) {
    const int l = threadIdx.x;
    const int mBase = blockIdx.x * 16;
    const int nBase = blockIdx.y * 32;
    const int rc = l & 15, kg = l >> 4;

    const ushort* pa  = xb + (mBase + rc) * F_IN + kg * 8;
    const ushort* pb0 = wt + (nBase + rc) * F_IN + kg * 8;
    const ushort* pb1 = pb0 + 16 * F_IN;

    f32x4 acc0 = {0.f, 0.f, 0.f, 0.f};
    f32x4 acc1 = {0.f, 0.f, 0.f, 0.f};

    #pragma unroll
    for (int ks = 0; ks < 16; ++ks) {
        bf16x8 a  = *(const bf16x8*)(pa  + ks * 32);
        bf16x8 b0 = *(const bf16x8*)(pb0 + ks * 32);
        bf16x8 b1 = *(const bf16x8*)(pb1 + ks * 32);
        acc0 = __builtin_amdgcn_mfma_f32_16x16x32_bf16(a, b0, acc0, 0, 0, 0);
        acc1 = __builtin_amdgcn_mfma_f32_16x16x32_bf16(a, b1, acc1, 0, 0, 0);
    }

    #pragma unroll
    for (int r = 0; r < 4; ++r) {
        act[(mBase + kg * 4 + r) * N_COLS + nBase + rc]      = acc0[r];
        act[(mBase + kg * 4 + r) * N_COLS + nBase + 16 + rc] = acc1[r];
    }
}

// ---------------- Pairwise L1 + exp-sum, 4 rows/thread, XOR-swizzled LDS ----------------
// Grid (50, 16): block = (kernel k, 32-row chunk). 256 threads = 8 row-threads x 32 q.
// Row-thread rt owns 4 rows; q owns 16 b2 values.
// LDS layout: logical float4 slot s = b2*4 + j stored at physical p = s ^ ((s>>6)&7)
// so loop reads (q-stride 1024B) spread across all 8 bank-quads.
__global__ __launch_bounds__(256) void pairwise_kernel(const float* __restrict__ act,
                                                       float* __restrict__ out) {
    const int k = blockIdx.x;          // 0..49
    const int chunk = blockIdx.y;      // 0..15
    __shared__ float4 Av[B_ROWS * 4];  // 32 KB, swizzled

    const int tid = threadIdx.x;
    const float* base = act + k * DK;
    #pragma unroll
    for (int i = 0; i < 8; ++i) {
        int idx = tid + i * 256;       // logical slot 0..2047
        int b = idx >> 2, d4 = idx & 3;
        Av[idx ^ ((idx >> 6) & 7)] = *(const float4*)(base + b * N_COLS + d4 * 4);
    }
    __syncthreads();

    const int rt = tid >> 5;           // 0..7 -> 4 rows each
    const int q = tid & 31;            // 0..31 -> 16 b2 each
    const int row0 = chunk * 32 + rt * 4;

    // load 4 m-rows into registers (one-time, swizzled addressing)
    float4 m[4][4];
    #pragma unroll
    for (int r = 0; r < 4; ++r) {
        int gr = row0 + r;
        int xr = (gr >> 4) & 7;
        #pragma unroll
        for (int j = 0; j < 4; ++j)
            m[r][j] = Av[(gr * 4 + j) ^ xr];
    }

    const float4* bq = Av + q * 64;    // this thread's b2-region (16 b2 x 4 slots)
    const int xm = q & 7;

    float acc[4] = {0.f, 0.f, 0.f, 0.f};
    #pragma unroll 4
    for (int i = 0; i < 16; ++i) {
        float4 v0 = bq[(i * 4 + 0) ^ xm];
        float4 v1 = bq[(i * 4 + 1) ^ xm];
        float4 v2 = bq[(i * 4 + 2) ^ xm];
        float4 v3 = bq[(i * 4 + 3) ^ xm];
        #pragma unroll
        for (int r = 0; r < 4; ++r) {
            float s0 = fabsf(m[r][0].x - v0.x) + fabsf(m[r][0].y - v0.y)
                     + fabsf(m[r][0].z - v0.z) + fabsf(m[r][0].w - v0.w);
            float s1 = fabsf(m[r][1].x - v1.x) + fabsf(m[r][1].y - v1.y)
                     + fabsf(m[r][1].z - v1.z) + fabsf(m[r][1].w - v1.w);
            float s2 = fabsf(m[r][2].x - v2.x) + fabsf(m[r][2].y - v2.y)
                     + fabsf(m[r][2].z - v2.z) + fabsf(m[r][2].w - v2.w);
            float s3 = fabsf(m[r][3].x - v3.x) + fabsf(m[r][3].y - v3.y)
                     + fabsf(m[r][3].z - v3.z) + fabsf(m[r][3].w - v3.w);
            float l1 = (s0 + s1) + (s2 + s3);
            acc[r] += EXP2F(l1 * -1.4426950408889634f);
        }
    }

    // reduce over the 32 q-lanes (xor masks stay within 32-lane halves)
    #pragma unroll
    for (int r = 0; r < 4; ++r) {
        acc[r] += __shfl_xor(acc[r], 1);
        acc[r] += __shfl_xor(acc[r], 2);
        acc[r] += __shfl_xor(acc[r], 4);
        acc[r] += __shfl_xor(acc[r], 8);
        acc[r] += __shfl_xor(acc[r], 16);
    }
    if (q == 0) {
        #pragma unroll
        for (int r = 0; r < 4; ++r)
            out[(row0 + r) * OUT_COLS + F_IN + k] = acc[r];
    }
}

extern "C" void kernel_launch(void* const* d_in, const int* in_sizes, int n_in,
                              void* d_out, int out_size, void* d_ws, size_t ws_size,
                              hipStream_t stream) {
    const float* x = (const float*)d_in[0];   // (512, 512) fp32
    const float* W = (const float*)d_in[1];   // (512, 800) fp32
    float* out = (float*)d_out;               // (512, 562) fp32

    char* ws = (char*)d_ws;
    ushort* xb = (ushort*)ws;                          // 512 KB
    ushort* wt = (ushort*)(ws + (512 * 1024));         // 800 KB
    float* act = (float*)(ws + (512 + 800) * 1024);    // 1.6 MB

    prep_kernel<<<dim3(528), dim3(256), 0, stream>>>(x, W, xb, wt, out);
    gemm_mfma_kernel<<<dim3(32, 25), dim3(64), 0, stream>>>(xb, wt, act);
    pairwise_kernel<<<dim3(50, 16), dim3(256), 0, stream>>>(act, out);
}

// Round 4
// 35.617 us; speedup vs baseline: 1.4733x; 1.1196x over previous
//
#include <hip/hip_runtime.h>
#include <hip/hip_bf16.h>

// MiniBatchDiscrimination: out = concat([x, sum_b2 exp(-L1(act_b, act_b2))], axis=1)
// B=512, F=512, K=50, D=16.  act = x @ W : (512, 800).
// Round 4: dispatch-count experiment. 3 kernels -> 2: prep eliminated, GEMM reads
// x/W fp32 directly with in-register bf16 conversion; x-copy folded into nb==0 blocks.

#define B_ROWS 512
#define F_IN   512
#define NK     50
#define DK     16
#define N_COLS (NK * DK)      // 800
#define OUT_COLS (F_IN + NK)  // 562

#if __has_builtin(__builtin_amdgcn_exp2f)
#define EXP2F __builtin_amdgcn_exp2f
#else
#define EXP2F exp2f
#endif

typedef __attribute__((ext_vector_type(8))) short bf16x8;
typedef __attribute__((ext_vector_type(4))) float f32x4;

__device__ __forceinline__ short bfs(float f) {
    __hip_bfloat16 h = __float2bfloat16(f);   // RNE; compiler fuses pairs to v_cvt_pk_bf16_f32
    return *reinterpret_cast<short*>(&h);
}

// ---------------- GEMM: act[512][800] = bf16(x) @ bf16(W) via 16x16x32 MFMA ----------------
// 1 wave per block; block (mb, nb) computes rows mb*16..+15, cols nb*32..+31 (2 frags).
// A frag: lane l holds x[mBase + (l&15)][ks*32 + 8*(l>>4) + j]  (2 float4 loads + cvt)
// B frag: lane l holds W[ks*32 + 8*(l>>4) + j][nBase + nf*16 + (l&15)] (8 strided dword loads + cvt)
// C/D:    col = l&15, row = (l>>4)*4 + reg   [m89 verified]
// nb==0 blocks additionally copy their 16 x-rows into out[:, 0:512].
__global__ __launch_bounds__(64) void gemm_direct_kernel(const float* __restrict__ x,
                                                         const float* __restrict__ W,
                                                         float* __restrict__ act,
                                                         float* __restrict__ out) {
    const int l = threadIdx.x;
    const int mBase = blockIdx.x * 16;
    const int nBase = blockIdx.y * 32;
    const int rc = l & 15, kg = l >> 4;

    if (blockIdx.y == 0) {
        // passthrough copy: 16 rows x 512 f32 = 2048 float4, 32 per lane
        #pragma unroll
        for (int i = 0; i < 32; ++i) {
            int idx = l + i * 64;            // 0..2047
            int r = idx >> 7, c4 = idx & 127;
            float4 v = *(const float4*)(x + (mBase + r) * F_IN + c4 * 4);
            float* o = out + (mBase + r) * OUT_COLS + c4 * 4;   // 8B-aligned (562 even)
            *(float2*)o = make_float2(v.x, v.y);
            *(float2*)(o + 2) = make_float2(v.z, v.w);
        }
    }

    const float* pa = x + (mBase + rc) * F_IN + kg * 8;
    const float* pb = W + (kg * 8) * N_COLS + nBase + rc;

    f32x4 acc0 = {0.f, 0.f, 0.f, 0.f};
    f32x4 acc1 = {0.f, 0.f, 0.f, 0.f};

    #pragma unroll
    for (int ks = 0; ks < 16; ++ks) {
        // A fragment: 8 consecutive fp32 along K
        float4 a0 = *(const float4*)(pa + ks * 32);
        float4 a1 = *(const float4*)(pa + ks * 32 + 4);
        bf16x8 a;
        a[0] = bfs(a0.x); a[1] = bfs(a0.y); a[2] = bfs(a0.z); a[3] = bfs(a0.w);
        a[4] = bfs(a1.x); a[5] = bfs(a1.y); a[6] = bfs(a1.z); a[7] = bfs(a1.w);

        // B fragments: 8 K-strided scalars per n-frag
        const float* pk = pb + (ks * 32) * N_COLS;
        bf16x8 b0, b1;
        #pragma unroll
        for (int j = 0; j < 8; ++j) {
            b0[j] = bfs(pk[j * N_COLS]);
            b1[j] = bfs(pk[j * N_COLS + 16]);
        }

        acc0 = __builtin_amdgcn_mfma_f32_16x16x32_bf16(a, b0, acc0, 0, 0, 0);
        acc1 = __builtin_amdgcn_mfma_f32_16x16x32_bf16(a, b1, acc1, 0, 0, 0);
    }

    #pragma unroll
    for (int r = 0; r < 4; ++r) {
        act[(mBase + kg * 4 + r) * N_COLS + nBase + rc]      = acc0[r];
        act[(mBase + kg * 4 + r) * N_COLS + nBase + 16 + rc] = acc1[r];
    }
}

// ---------------- Pairwise L1 + exp-sum, 4 rows/thread, XOR-swizzled LDS ----------------
// Grid (50, 16): block = (kernel k, 32-row chunk). 256 threads = 8 row-threads x 32 q.
// LDS: logical float4 slot s = b2*4 + j stored at physical s ^ ((s>>6)&7).
__global__ __launch_bounds__(256) void pairwise_kernel(const float* __restrict__ act,
                                                       float* __restrict__ out) {
    const int k = blockIdx.x;          // 0..49
    const int chunk = blockIdx.y;      // 0..15
    __shared__ float4 Av[B_ROWS * 4];  // 32 KB, swizzled

    const int tid = threadIdx.x;
    const float* base = act + k * DK;
    #pragma unroll
    for (int i = 0; i < 8; ++i) {
        int idx = tid + i * 256;       // logical slot 0..2047
        int b = idx >> 2, d4 = idx & 3;
        Av[idx ^ ((idx >> 6) & 7)] = *(const float4*)(base + b * N_COLS + d4 * 4);
    }
    __syncthreads();

    const int rt = tid >> 5;           // 0..7 -> 4 rows each
    const int q = tid & 31;            // 0..31 -> 16 b2 each
    const int row0 = chunk * 32 + rt * 4;

    float4 m[4][4];
    #pragma unroll
    for (int r = 0; r < 4; ++r) {
        int gr = row0 + r;
        int xr = (gr >> 4) & 7;
        #pragma unroll
        for (int j = 0; j < 4; ++j)
            m[r][j] = Av[(gr * 4 + j) ^ xr];
    }

    const float4* bq = Av + q * 64;    // 16 b2 x 4 slots
    const int xm = q & 7;

    float acc[4] = {0.f, 0.f, 0.f, 0.f};
    #pragma unroll 4
    for (int i = 0; i < 16; ++i) {
        float4 v0 = bq[(i * 4 + 0) ^ xm];
        float4 v1 = bq[(i * 4 + 1) ^ xm];
        float4 v2 = bq[(i * 4 + 2) ^ xm];
        float4 v3 = bq[(i * 4 + 3) ^ xm];
        #pragma unroll
        for (int r = 0; r < 4; ++r) {
            float s0 = fabsf(m[r][0].x - v0.x) + fabsf(m[r][0].y - v0.y)
                     + fabsf(m[r][0].z - v0.z) + fabsf(m[r][0].w - v0.w);
            float s1 = fabsf(m[r][1].x - v1.x) + fabsf(m[r][1].y - v1.y)
                     + fabsf(m[r][1].z - v1.z) + fabsf(m[r][1].w - v1.w);
            float s2 = fabsf(m[r][2].x - v2.x) + fabsf(m[r][2].y - v2.y)
                     + fabsf(m[r][2].z - v2.z) + fabsf(m[r][2].w - v2.w);
            float s3 = fabsf(m[r][3].x - v3.x) + fabsf(m[r][3].y - v3.y)
                     + fabsf(m[r][3].z - v3.z) + fabsf(m[r][3].w - v3.w);
            float l1 = (s0 + s1) + (s2 + s3);
            acc[r] += EXP2F(l1 * -1.4426950408889634f);
        }
    }

    #pragma unroll
    for (int r = 0; r < 4; ++r) {
        acc[r] += __shfl_xor(acc[r], 1);
        acc[r] += __shfl_xor(acc[r], 2);
        acc[r] += __shfl_xor(acc[r], 4);
        acc[r] += __shfl_xor(acc[r], 8);
        acc[r] += __shfl_xor(acc[r], 16);
    }
    if (q == 0) {
        #pragma unroll
        for (int r = 0; r < 4; ++r)
            out[(row0 + r) * OUT_COLS + F_IN + k] = acc[r];
    }
}

extern "C" void kernel_launch(void* const* d_in, const int* in_sizes, int n_in,
                              void* d_out, int out_size, void* d_ws, size_t ws_size,
                              hipStream_t stream) {
    const float* x = (const float*)d_in[0];   // (512, 512) fp32
    const float* W = (const float*)d_in[1];   // (512, 800) fp32
    float* out = (float*)d_out;               // (512, 562) fp32
    float* act = (float*)d_ws;                // (512, 800) fp32 scratch

    gemm_direct_kernel<<<dim3(32, 25), dim3(64), 0, stream>>>(x, W, act, out);
    pairwise_kernel<<<dim3(50, 16), dim3(256), 0, stream>>>(act, out);
}

// Round 7
// 32.048 us; speedup vs baseline: 1.6373x; 1.1114x over previous
//
#include <hip/hip_runtime.h>
#include <hip/hip_bf16.h>
#include <hip/hip_fp16.h>

// MiniBatchDiscrimination: out = concat([x, sum_b2 exp(-L1(act_b, act_b2))], axis=1)
// B=512, F=512, K=50, D=16.  act = x @ W : (512, 800).
// Round 7: proven 2-dispatch structure (R4) + two safe in-kernel wins:
//  (1) GEMM K-split x4: 800 blocks x 256 thr, wave w owns K in [w*128,+128), LDS reduce.
//  (2) pairwise in packed f16 (v_pk_* via __hsub2/__habs2/__hadd2), ~25% fewer VALU ops.

#define B_ROWS 512
#define F_IN   512
#define NK     50
#define DK     16
#define N_COLS (NK * DK)      // 800
#define OUT_COLS (F_IN + NK)  // 562

#if __has_builtin(__builtin_amdgcn_exp2f)
#define EXP2F __builtin_amdgcn_exp2f
#else
#define EXP2F exp2f
#endif

typedef __attribute__((ext_vector_type(8))) short bf16x8;
typedef __attribute__((ext_vector_type(4))) float f32x4;

__device__ __forceinline__ short bfs(float f) {
    __hip_bfloat16 h = __float2bfloat16(f);   // RNE; pairs fuse to v_cvt_pk_bf16_f32
    return *reinterpret_cast<short*>(&h);
}

// ---------------- GEMM: act[512][800] = bf16(x) @ bf16(W), K split over 4 waves ----------------
// Grid (32, 25), 256 threads. Block (bx, by) -> rows bx*16..+15, cols by*32..+31.
// Wave w handles K in [w*128, w*128+128) : 4 MFMA steps; cross-wave LDS reduce.
// A frag: lane l holds x[mBase + (l&15)][kOff + 8*(l>>4) + j]
// B frag: lane l holds W[kOff + 8*(l>>4) + j][nBase + fr*16 + (l&15)]
// C/D:    col = l&15, row = (l>>4)*4 + reg   [m89 verified]
// Blocks with flat id < 128 also copy x rows into out[:, 0:512].
__global__ __launch_bounds__(256) void gemm_ksplit_kernel(const float* __restrict__ x,
                                                          const float* __restrict__ W,
                                                          float* __restrict__ act,
                                                          float* __restrict__ out) {
    __shared__ float red[4 * 64 * 8];   // 8 KB: [wave][lane][8]

    const int tid = threadIdx.x;
    const int wave = tid >> 6, l = tid & 63;
    const int bid = blockIdx.y * 32 + blockIdx.x;   // 0..799

    // x passthrough copy on 128 blocks (2 float4 per thread)
    if (bid < 128) {
        #pragma unroll
        for (int i = 0; i < 2; ++i) {
            int gid = bid * 512 + i * 256 + tid;    // 0..65535
            int row = gid >> 7, c4 = gid & 127;
            float4 v = ((const float4*)x)[gid];
            float* o = out + row * OUT_COLS + c4 * 4;   // 8B-aligned (562 even)
            *(float2*)o = make_float2(v.x, v.y);
            *(float2*)(o + 2) = make_float2(v.z, v.w);
        }
    }

    const int mBase = blockIdx.x * 16;
    const int nBase = blockIdx.y * 32;
    const int rc = l & 15, kg = l >> 4;

    const float* pa = x + (mBase + rc) * F_IN + wave * 128 + kg * 8;
    const float* pb = W + (wave * 128 + kg * 8) * N_COLS + nBase + rc;

    f32x4 acc0 = {0.f, 0.f, 0.f, 0.f};
    f32x4 acc1 = {0.f, 0.f, 0.f, 0.f};

    #pragma unroll
    for (int ks = 0; ks < 4; ++ks) {
        float4 a0 = *(const float4*)(pa + ks * 32);
        float4 a1 = *(const float4*)(pa + ks * 32 + 4);
        bf16x8 a;
        a[0] = bfs(a0.x); a[1] = bfs(a0.y); a[2] = bfs(a0.z); a[3] = bfs(a0.w);
        a[4] = bfs(a1.x); a[5] = bfs(a1.y); a[6] = bfs(a1.z); a[7] = bfs(a1.w);

        const float* pk = pb + (ks * 32) * N_COLS;
        bf16x8 b0, b1;
        #pragma unroll
        for (int j = 0; j < 8; ++j) {
            b0[j] = bfs(pk[j * N_COLS]);
            b1[j] = bfs(pk[j * N_COLS + 16]);
        }
        acc0 = __builtin_amdgcn_mfma_f32_16x16x32_bf16(a, b0, acc0, 0, 0, 0);
        acc1 = __builtin_amdgcn_mfma_f32_16x16x32_bf16(a, b1, acc1, 0, 0, 0);
    }

    // cross-wave reduce: red[wave][lane][0..3]=acc0, [4..7]=acc1
    const int ro = (wave * 64 + l) * 8;
    *(f32x4*)(red + ro)     = acc0;
    *(f32x4*)(red + ro + 4) = acc1;
    __syncthreads();

    // each thread sums one float2 (elements e, e+1) over the 4 waves and stores.
    // e = 2*tid: le = e>>3 (lane), j0 = e&7; j<4 -> acc0[j] (fr=0), j>=4 -> acc1[j-4] (fr=1).
    // rows (j0&3) and (j0&3)+1, same column.
    {
        const int e = tid * 2;
        const int le = e >> 3, j0 = e & 7;
        float2 s = make_float2(0.f, 0.f);
        #pragma unroll
        for (int w = 0; w < 4; ++w) {
            float2 v = *(const float2*)(red + w * 512 + e);
            s.x += v.x; s.y += v.y;
        }
        const int row = mBase + (le >> 4) * 4 + (j0 & 3);
        const int col = nBase + (le & 15) + (j0 >> 2) * 16;
        act[row * N_COLS + col]       = s.x;
        act[(row + 1) * N_COLS + col] = s.y;
    }
}

// ---------------- Pairwise L1 + exp-sum, packed f16, 4 rows/thread ----------------
// Grid (50, 16): block = (kernel k, 32-row chunk). 256 threads = 8 row-threads x 32 q.
// LDS: row b as 4 half4 (uint2) slots; logical slot s = b*4 + j stored at s ^ ((s>>6)&15)
// so q-group reads (stride 64 slots = 512B) spread across all 16 bank-pairs.
__global__ __launch_bounds__(256) void pairwise_h2_kernel(const float* __restrict__ act,
                                                          float* __restrict__ out) {
    const int k = blockIdx.x;          // 0..49
    const int chunk = blockIdx.y;      // 0..15
    __shared__ uint2 Ah4[B_ROWS * 4];  // 16 KB, swizzled half4 slots

    const int tid = threadIdx.x;
    const float* base = act + k * DK;
    #pragma unroll
    for (int i = 0; i < 8; ++i) {
        int idx = tid + i * 256;       // logical slot 0..2047
        int b = idx >> 2, d4 = idx & 3;
        float4 v = *(const float4*)(base + b * N_COLS + d4 * 4);
        __half2 h0 = __float22half2_rn(make_float2(v.x, v.y));
        __half2 h1 = __float22half2_rn(make_float2(v.z, v.w));
        uint2 u;
        u.x = __builtin_bit_cast(unsigned, h0);
        u.y = __builtin_bit_cast(unsigned, h1);
        Ah4[idx ^ ((idx >> 6) & 15)] = u;
    }
    __syncthreads();

    const int rt = tid >> 5;           // 0..7 -> 4 rows each
    const int q = tid & 31;            // 0..31 -> 16 b2 each
    const int row0 = chunk * 32 + rt * 4;

    // 4 m-rows in registers: 8 half2 per row
    __half2 m[4][8];
    #pragma unroll
    for (int r = 0; r < 4; ++r) {
        int gr = row0 + r;
        int xr = (gr >> 4) & 15;
        #pragma unroll
        for (int j = 0; j < 4; ++j) {
            uint2 u = Ah4[(gr * 4 + j) ^ xr];
            m[r][2 * j]     = __builtin_bit_cast(__half2, u.x);
            m[r][2 * j + 1] = __builtin_bit_cast(__half2, u.y);
        }
    }

    const uint2* bq = Ah4 + q * 64;    // 16 b2 x 4 slots
    const int xm = q & 15;

    float acc[4] = {0.f, 0.f, 0.f, 0.f};
    #pragma unroll 4
    for (int i = 0; i < 16; ++i) {
        __half2 v[8];
        #pragma unroll
        for (int j = 0; j < 4; ++j) {
            uint2 u = bq[(i * 4 + j) ^ xm];
            v[2 * j]     = __builtin_bit_cast(__half2, u.x);
            v[2 * j + 1] = __builtin_bit_cast(__half2, u.y);
        }
        #pragma unroll
        for (int r = 0; r < 4; ++r) {
            __half2 s = __habs2(__hsub2(m[r][0], v[0]));
            #pragma unroll
            for (int jj = 1; jj < 8; ++jj)
                s = __hadd2(s, __habs2(__hsub2(m[r][jj], v[jj])));
            float2 f = __half22float2(s);
            acc[r] += EXP2F((f.x + f.y) * -1.4426950408889634f);
        }
    }

    #pragma unroll
    for (int r = 0; r < 4; ++r) {
        acc[r] += __shfl_xor(acc[r], 1);
        acc[r] += __shfl_xor(acc[r], 2);
        acc[r] += __shfl_xor(acc[r], 4);
        acc[r] += __shfl_xor(acc[r], 8);
        acc[r] += __shfl_xor(acc[r], 16);
    }
    if (q == 0) {
        #pragma unroll
        for (int r = 0; r < 4; ++r)
            out[(row0 + r) * OUT_COLS + F_IN + k] = acc[r];
    }
}

extern "C" void kernel_launch(void* const* d_in, const int* in_sizes, int n_in,
                              void* d_out, int out_size, void* d_ws, size_t ws_size,
                              hipStream_t stream) {
    const float* x = (const float*)d_in[0];   // (512, 512) fp32
    const float* W = (const float*)d_in[1];   // (512, 800) fp32
    float* out = (float*)d_out;               // (512, 562) fp32
    float* act = (float*)d_ws;                // (512, 800) fp32 scratch

    gemm_ksplit_kernel<<<dim3(32, 25), dim3(256), 0, stream>>>(x, W, act, out);
    pairwise_h2_kernel<<<dim3(50, 16), dim3(256), 0, stream>>>(act, out);
}